// Round 2
// baseline (670.001 us; speedup 1.0000x reference)
//
#include <hip/hip_runtime.h>
#include <hip/hip_bf16.h>
#include <math.h>

#define T_TOK 8192
#define EMB   1024
#define HID   1536
#define NE    8

typedef float  floatx4 __attribute__((ext_vector_type(4)));
typedef __bf16 bf16x8  __attribute__((ext_vector_type(8)));
typedef __bf16 bf16x4  __attribute__((ext_vector_type(4)));

// ---- workspace layout (bytes) ----
#define WS_COUNTS   0           // 8 * 4
#define WS_OFFSETS  1024        // 9 * 4
#define WS_FLAGS    2048        // 7 * 4  (1 = tensor i is fp32, 0 = bf16)
#define WS_TOKLIST  4096        // 8 * 8192 * 4 = 262144
#define WS_OUTACC   266240      // T*E*4 = 33554432
#define WS_W1T      33820672    // 8*1536*1024*2 = 25165824
#define WS_W2T      58986496    // 25165824
#define WS_H        84152320    // 16640 * 1536 * 2 = 51118080
#define WS_NEEDED   135270400

// ---- dual-dtype scalar load ----
__device__ __forceinline__ float eload(const void* p, size_t idx, bool f32) {
  return f32 ? ((const float*)p)[idx] : (float)(((const __bf16*)p)[idx]);
}

// ---- dual-dtype 8-element (16B-as-bf16) load ----
__device__ __forceinline__ bf16x8 ld8(const void* p, size_t idx, bool f32) {
  if (f32) {
    const float* g = (const float*)p + idx;
    float4 u = *(const float4*)g;
    float4 v = *(const float4*)(g + 4);
    bf16x8 r;
    r[0] = (__bf16)u.x; r[1] = (__bf16)u.y; r[2] = (__bf16)u.z; r[3] = (__bf16)u.w;
    r[4] = (__bf16)v.x; r[5] = (__bf16)v.y; r[6] = (__bf16)v.z; r[7] = (__bf16)v.w;
    return r;
  }
  return *(const bf16x8*)((const __bf16*)p + idx);
}

// ---------------- dtype sniff: one block per input tensor ----------------
// fp32 data from N(0,1)/uniform has fp32 exponent field ~[100,150].
// bf16-pair words have exponent field ~0/1 or >=234. Count and vote.
__global__ __launch_bounds__(256)
void sniff_kernel(const void* p0, const void* p1, const void* p2, const void* p3,
                  const void* p4, const void* p5, const void* p6, int* flags) {
  const void* ps[7] = {p0, p1, p2, p3, p4, p5, p6};
  const int nelem[7] = {T_TOK * EMB, EMB * NE, NE, NE * EMB * HID, NE * HID, NE * HID * EMB, NE * EMB};
  int t = blockIdx.x;
  const unsigned* w = (const unsigned*)ps[t];
  int nw = nelem[t] / 2;              // safe even if data is bf16 (n*2 bytes)
  if (nw > 2048) nw = 2048;
  __shared__ int s_pl, s_nz;
  if (threadIdx.x == 0) { s_pl = 0; s_nz = 0; }
  __syncthreads();
  int pl = 0, nz = 0;
  for (int i = threadIdx.x; i < nw; i += 256) {
    unsigned v = w[i];
    if (v == 0) continue;
    nz++;
    unsigned e = (v >> 23) & 0xFF;
    if (e >= 100 && e <= 150) pl++;
  }
  atomicAdd(&s_pl, pl);
  atomicAdd(&s_nz, nz);
  __syncthreads();
  if (threadIdx.x == 0) flags[t] = (2 * s_pl > s_nz) ? 1 : 0;
}

// ---------------- router: one wave per token ----------------
__global__ __launch_bounds__(256)
void router_kernel(const void* __restrict__ x, const void* __restrict__ Wr,
                   const void* __restrict__ br, const int* __restrict__ kptr,
                   const int* __restrict__ flags,
                   int* __restrict__ counts, int* __restrict__ tok_list) {
  const bool xf32  = flags[0] != 0;
  const bool wrf32 = flags[1] != 0;
  const bool brf32 = flags[2] != 0;
  int wid  = (blockIdx.x * blockDim.x + threadIdx.x) >> 6;
  int lane = threadIdx.x & 63;
  if (wid >= T_TOK) return;
  float acc[NE];
#pragma unroll
  for (int e = 0; e < NE; ++e) acc[e] = 0.f;
  for (int i = lane; i < EMB; i += 64) {
    float xv = eload(x, (size_t)wid * EMB + i, xf32);
    if (wrf32) {
      const float* wr = (const float*)Wr + (size_t)i * NE;
#pragma unroll
      for (int e = 0; e < NE; ++e) acc[e] += xv * wr[e];
    } else {
      bf16x8 wv = *(const bf16x8*)((const __bf16*)Wr + (size_t)i * NE);
#pragma unroll
      for (int e = 0; e < NE; ++e) acc[e] += xv * (float)wv[e];
    }
  }
#pragma unroll
  for (int e = 0; e < NE; ++e) {
#pragma unroll
    for (int off = 32; off > 0; off >>= 1)
      acc[e] += __shfl_xor(acc[e], off, 64);
  }
  if (lane == 0) {
    int k = kptr[0];
    if (k < 1 || k > NE) k = 1;
    float lg[NE];
#pragma unroll
    for (int e = 0; e < NE; ++e) lg[e] = acc[e] + eload(br, e, brf32);
    for (int s = 0; s < k; ++s) {
      int bi = 0; float bv = lg[0];
#pragma unroll
      for (int e = 1; e < NE; ++e) { if (lg[e] > bv) { bv = lg[e]; bi = e; } }
      lg[bi] = -3.0e38f;
      int pos = atomicAdd(&counts[bi], 1);
      tok_list[bi * T_TOK + pos] = wid;
    }
  }
}

__global__ void offsets_kernel(const int* __restrict__ counts, int* __restrict__ offsets) {
  if (threadIdx.x == 0 && blockIdx.x == 0) {
    int s = 0;
    for (int e = 0; e < NE; ++e) { offsets[e] = s; s += counts[e]; }
    offsets[NE] = s;
  }
}

// ---------------- per-expert transpose: in [K][N] -> out [N][K] (bf16) ----------------
__global__ __launch_bounds__(256)
void transpose_kernel(const void* __restrict__ in, __bf16* __restrict__ out, int K, int N,
                      const int* __restrict__ flags, int fidx) {
  const bool f32 = flags[fidx] != 0;
  __shared__ __bf16 tile[64][65];
  size_t eoff = (size_t)blockIdx.z * (size_t)K * (size_t)N;
  int n0 = blockIdx.x * 64;
  int k0 = blockIdx.y * 64;
  int tx = threadIdx.x & 63;
  int ty = threadIdx.x >> 6;
#pragma unroll
  for (int i = 0; i < 16; ++i) {
    int r = i * 4 + ty;
    tile[r][tx] = (__bf16)eload(in, eoff + (size_t)(k0 + r) * N + (n0 + tx), f32);
  }
  __syncthreads();
#pragma unroll
  for (int i = 0; i < 16; ++i) {
    int r = i * 4 + ty;
    out[eoff + (size_t)(n0 + r) * K + (k0 + tx)] = tile[tx][r];
  }
}

// ---------------- GEMM1: h = gelu(x_gather @ W1[e] + b1[e]) ----------------
__global__ __launch_bounds__(256, 2)
void gemm1_kernel(const void* __restrict__ x, const __bf16* __restrict__ w1t,
                  const void* __restrict__ b1, const int* __restrict__ counts,
                  const int* __restrict__ offsets, const int* __restrict__ tok_list,
                  const int* __restrict__ flags, __bf16* __restrict__ hbuf) {
  const int e  = blockIdx.z;
  const int mT = blockIdx.y;
  const int nT = blockIdx.x;
  const int cnt = counts[e];
  if (mT * 128 >= cnt) return;
  const bool xf32  = flags[0] != 0;
  const bool b1f32 = flags[4] != 0;

  __shared__ __align__(16) __bf16 As[128 * 32];
  __shared__ __align__(16) __bf16 Bs[128 * 32];

  const int tid  = threadIdx.x;
  const int wave = tid >> 6;
  const int lane = tid & 63;

  const int sr = lane >> 2;            // staging row within 16-row group
  const int kc = (lane & 3) * 8;       // staging k-chunk (8 elems = 16B bf16)
  const int r0 = wave * 16 + sr;
  const int r1 = 64 + wave * 16 + sr;

  const int tokA0 = tok_list[e * T_TOK + mT * 128 + r0];  // pad entries are 0 (memset)
  const int tokA1 = tok_list[e * T_TOK + mT * 128 + r1];
  size_t offA0 = (size_t)tokA0 * EMB + kc;
  size_t offA1 = (size_t)tokA1 * EMB + kc;
  const __bf16* gB0 = w1t + ((size_t)e * HID + nT * 128 + r0) * EMB + kc;
  const __bf16* gB1 = w1t + ((size_t)e * HID + nT * 128 + r1) * EMB + kc;

  const int wm = (wave & 1) * 64;
  const int wn = (wave >> 1) * 64;
  const int mr = lane & 15;
  const int kq = (lane >> 4) * 8;

  floatx4 acc[4][4];
#pragma unroll
  for (int i = 0; i < 4; ++i)
#pragma unroll
    for (int j = 0; j < 4; ++j) acc[i][j] = (floatx4){0.f, 0.f, 0.f, 0.f};

  for (int kb = 0; kb < EMB / 32; ++kb) {
    bf16x8 a0 = ld8(x, offA0, xf32);
    bf16x8 a1 = ld8(x, offA1, xf32);
    bf16x8 b0 = *(const bf16x8*)gB0;
    bf16x8 b1v = *(const bf16x8*)gB1;
    offA0 += 32; offA1 += 32; gB0 += 32; gB1 += 32;
    __syncthreads();                       // previous iteration's readers done
    *(bf16x8*)(As + r0 * 32 + kc) = a0;
    *(bf16x8*)(As + r1 * 32 + kc) = a1;
    *(bf16x8*)(Bs + r0 * 32 + kc) = b0;
    *(bf16x8*)(Bs + r1 * 32 + kc) = b1v;
    __syncthreads();                       // staging visible
    bf16x8 af[4], bfr[4];
#pragma unroll
    for (int i = 0; i < 4; ++i) af[i]  = *(const bf16x8*)(As + (wm + i * 16 + mr) * 32 + kq);
#pragma unroll
    for (int j = 0; j < 4; ++j) bfr[j] = *(const bf16x8*)(Bs + (wn + j * 16 + mr) * 32 + kq);
#pragma unroll
    for (int i = 0; i < 4; ++i)
#pragma unroll
      for (int j = 0; j < 4; ++j)
        acc[i][j] = __builtin_amdgcn_mfma_f32_16x16x32_bf16(af[i], bfr[j], acc[i][j], 0, 0, 0);
  }

  // epilogue: C/D layout col=lane&15, row=(lane>>4)*4+reg
  const int hBase   = offsets[e] + mT * 128;
  const int colBase = nT * 128 + wn + mr;
  float b1v4[4];
#pragma unroll
  for (int j = 0; j < 4; ++j) b1v4[j] = eload(b1, (size_t)e * HID + colBase + j * 16, b1f32);
#pragma unroll
  for (int i = 0; i < 4; ++i) {
    const int rowLoc = wm + i * 16 + (lane >> 4) * 4;
#pragma unroll
    for (int r = 0; r < 4; ++r) {
      const int row = rowLoc + r;
      if (mT * 128 + row < cnt) {
        __bf16* hp = hbuf + (size_t)(hBase + row) * HID + colBase;
#pragma unroll
        for (int j = 0; j < 4; ++j) {
          float v = acc[i][j][r] + b1v4[j];
          float g = 0.5f * v * (1.0f + erff(v * 0.70710678118654752f));
          hp[j * 16] = (__bf16)g;
        }
      }
    }
  }
}

// ---------------- GEMM2: out_acc[tok] += (h @ W2[e] + b2[e]) / k ----------------
__global__ __launch_bounds__(256, 2)
void gemm2_kernel(const __bf16* __restrict__ hbuf, const __bf16* __restrict__ w2t,
                  const void* __restrict__ b2, const int* __restrict__ counts,
                  const int* __restrict__ offsets, const int* __restrict__ tok_list,
                  const int* __restrict__ kptr, const int* __restrict__ flags,
                  float* __restrict__ out_acc) {
  const int e  = blockIdx.z;
  const int mT = blockIdx.y;
  const int nT = blockIdx.x;
  const int cnt = counts[e];
  if (mT * 128 >= cnt) return;
  const bool b2f32 = flags[6] != 0;

  __shared__ __align__(16) __bf16 As[128 * 32];
  __shared__ __align__(16) __bf16 Bs[128 * 32];

  const int tid  = threadIdx.x;
  const int wave = tid >> 6;
  const int lane = tid & 63;

  const int sr = lane >> 2;
  const int kc = (lane & 3) * 8;
  const int r0 = wave * 16 + sr;
  const int r1 = 64 + wave * 16 + sr;

  const int hRowBase = offsets[e] + mT * 128;   // contiguous per expert; tail slack exists
  const __bf16* gA0 = hbuf + (size_t)(hRowBase + r0) * HID + kc;
  const __bf16* gA1 = hbuf + (size_t)(hRowBase + r1) * HID + kc;
  const __bf16* gB0 = w2t + ((size_t)e * EMB + nT * 128 + r0) * HID + kc;
  const __bf16* gB1 = w2t + ((size_t)e * EMB + nT * 128 + r1) * HID + kc;

  const int wm = (wave & 1) * 64;
  const int wn = (wave >> 1) * 64;
  const int mr = lane & 15;
  const int kq = (lane >> 4) * 8;

  floatx4 acc[4][4];
#pragma unroll
  for (int i = 0; i < 4; ++i)
#pragma unroll
    for (int j = 0; j < 4; ++j) acc[i][j] = (floatx4){0.f, 0.f, 0.f, 0.f};

  for (int kb = 0; kb < HID / 32; ++kb) {
    bf16x8 a0 = *(const bf16x8*)gA0;
    bf16x8 a1 = *(const bf16x8*)gA1;
    bf16x8 b0 = *(const bf16x8*)gB0;
    bf16x8 b1v = *(const bf16x8*)gB1;
    gA0 += 32; gA1 += 32; gB0 += 32; gB1 += 32;
    __syncthreads();
    *(bf16x8*)(As + r0 * 32 + kc) = a0;
    *(bf16x8*)(As + r1 * 32 + kc) = a1;
    *(bf16x8*)(Bs + r0 * 32 + kc) = b0;
    *(bf16x8*)(Bs + r1 * 32 + kc) = b1v;
    __syncthreads();
    bf16x8 af[4], bfr[4];
#pragma unroll
    for (int i = 0; i < 4; ++i) af[i]  = *(const bf16x8*)(As + (wm + i * 16 + mr) * 32 + kq);
#pragma unroll
    for (int j = 0; j < 4; ++j) bfr[j] = *(const bf16x8*)(Bs + (wn + j * 16 + mr) * 32 + kq);
#pragma unroll
    for (int i = 0; i < 4; ++i)
#pragma unroll
      for (int j = 0; j < 4; ++j)
        acc[i][j] = __builtin_amdgcn_mfma_f32_16x16x32_bf16(af[i], bfr[j], acc[i][j], 0, 0, 0);
  }

  int k = kptr[0];
  if (k < 1 || k > NE) k = 1;
  const float invk = 1.0f / (float)k;
  const int colBase = nT * 128 + wn + mr;
  float b2v4[4];
#pragma unroll
  for (int j = 0; j < 4; ++j) b2v4[j] = eload(b2, (size_t)e * EMB + colBase + j * 16, b2f32);
#pragma unroll
  for (int i = 0; i < 4; ++i) {
    const int rowLoc = wm + i * 16 + (lane >> 4) * 4;
#pragma unroll
    for (int r = 0; r < 4; ++r) {
      const int row = rowLoc + r;
      if (mT * 128 + row < cnt) {
        const int tok = tok_list[e * T_TOK + mT * 128 + row];
        float* op = out_acc + (size_t)tok * EMB + colBase;
#pragma unroll
        for (int j = 0; j < 4; ++j)
          atomicAdd(&op[j * 16], (acc[i][j][r] + b2v4[j]) * invk);
      }
    }
  }
}

// ---------------- fp32 accumulator -> output (dtype follows x's flag) ----------------
__global__ __launch_bounds__(256)
void convert_kernel(const float* __restrict__ acc, void* __restrict__ out,
                    const int* __restrict__ flags) {
  const bool f32 = flags[0] != 0;
  int idx = (blockIdx.x * 256 + threadIdx.x) * 4;
  float4 v = *(const float4*)(acc + idx);
  if (f32) {
    *(float4*)((float*)out + idx) = v;
  } else {
    bf16x4 o;
    o[0] = (__bf16)v.x; o[1] = (__bf16)v.y; o[2] = (__bf16)v.z; o[3] = (__bf16)v.w;
    *(bf16x4*)((__bf16*)out + idx) = o;
  }
}

extern "C" void kernel_launch(void* const* d_in, const int* in_sizes, int n_in,
                              void* d_out, int out_size, void* d_ws, size_t ws_size,
                              hipStream_t stream) {
  (void)in_sizes; (void)n_in; (void)out_size;
  if (ws_size < (size_t)WS_NEEDED) return;  // diagnosable: output stays 0 -> absmax == max|ref|

  const void* x  = d_in[0];
  const void* Wr = d_in[1];
  const void* br = d_in[2];
  const void* W1 = d_in[3];
  const void* b1 = d_in[4];
  const void* W2 = d_in[5];
  const void* b2 = d_in[6];
  const int* kptr = (const int*)d_in[7];

  char* ws = (char*)d_ws;
  int*    counts   = (int*)(ws + WS_COUNTS);
  int*    offsets  = (int*)(ws + WS_OFFSETS);
  int*    flags    = (int*)(ws + WS_FLAGS);
  int*    tok_list = (int*)(ws + WS_TOKLIST);
  float*  out_acc  = (float*)(ws + WS_OUTACC);
  __bf16* w1t      = (__bf16*)(ws + WS_W1T);
  __bf16* w2t      = (__bf16*)(ws + WS_W2T);
  __bf16* hbuf     = (__bf16*)(ws + WS_H);

  // zero control region (tok_list zeros double as safe pad tokens) + fp32 accumulator
  hipMemsetAsync(ws, 0, WS_OUTACC, stream);
  hipMemsetAsync(out_acc, 0, (size_t)T_TOK * EMB * 4, stream);

  sniff_kernel<<<dim3(7), 256, 0, stream>>>(x, Wr, br, W1, b1, W2, b2, flags);

  // weight transposes to bf16 [N][K] (MFMA needs K-contiguous operands)
  transpose_kernel<<<dim3(HID / 64, EMB / 64, NE), 256, 0, stream>>>(W1, w1t, EMB, HID, flags, 3);
  transpose_kernel<<<dim3(EMB / 64, HID / 64, NE), 256, 0, stream>>>(W2, w2t, HID, EMB, flags, 5);

  router_kernel<<<dim3(T_TOK / 4), 256, 0, stream>>>(x, Wr, br, kptr, flags, counts, tok_list);
  offsets_kernel<<<1, 64, 0, stream>>>(counts, offsets);

  gemm1_kernel<<<dim3(HID / 128, T_TOK / 128, NE), 256, 0, stream>>>(
      x, w1t, b1, counts, offsets, tok_list, flags, hbuf);
  gemm2_kernel<<<dim3(EMB / 128, T_TOK / 128, NE), 256, 0, stream>>>(
      hbuf, w2t, b2, counts, offsets, tok_list, kptr, flags, out_acc);

  convert_kernel<<<dim3((T_TOK * EMB) / 1024), 256, 0, stream>>>(out_acc, out_size ? d_out : d_out, flags);
}